// Round 2
// baseline (17634.631 us; speedup 1.0000x reference)
//
#include <hip/hip_runtime.h>
#include <hip/hip_bf16.h>
#include <hip/hip_cooperative_groups.h>

namespace cg = cooperative_groups;

// LSMPool round 2: persistent cooperative kernel for the 128 sequential
// reservoir steps. Grid 512 blocks (64 N-chunks x 8 K-splits) x 256 thr,
// 2 blocks/CU. Per step: K-split GEMM (BK=64, double-buffered LDS with
// XOR-swizzle) -> partials -> grid.sync -> deterministic reduce + LIF ->
// grid.sync. Readout GEMM + scan unchanged from round 1 (absmax=0.0).
// ws: w1hi 41.9M | w1lo 41.9M | xb 16.8M | spk 67.6M | w2hi 4.2M | w2lo 4.2M
//     | mem1 1.0M | cur2 16.8M | part 8.4M  (~194 MiB)

namespace {
constexpr int T_STEPS = 128;
constexpr int BATCH   = 64;
constexpr int IN_F    = 1024;
constexpr int HID     = 4096;
constexpr int OUT_F   = 512;
constexpr int TOTAL   = IN_F + HID;      // 5120
constexpr int KSPLIT  = 8;
constexpr int KPB     = TOTAL / KSPLIT;  // 640
constexpr int BK      = 64;
constexpr int NIT     = KPB / BK;        // 10
}

using bf16x8 = __attribute__((ext_vector_type(8))) short;   // 8 bf16
using f32x4  = __attribute__((ext_vector_type(4))) float;   // MFMA acc

// ---------------- prep kernels ----------------

__global__ void k_cvt_split(const float* __restrict__ src,
                            __hip_bfloat16* __restrict__ hi,
                            __hip_bfloat16* __restrict__ lo, int n4) {
  int i = blockIdx.x * blockDim.x + threadIdx.x;
  if (i >= n4) return;
  float4 v = reinterpret_cast<const float4*>(src)[i];
#define CVT1(J, F)                                                        \
  {                                                                       \
    __hip_bfloat16 hb = __float2bfloat16(F);                              \
    hi[4 * (size_t)i + J] = hb;                                           \
    lo[4 * (size_t)i + J] = __float2bfloat16((F) - __bfloat162float(hb)); \
  }
  CVT1(0, v.x) CVT1(1, v.y) CVT1(2, v.z) CVT1(3, v.w)
#undef CVT1
}

__global__ void k_cvt_x(const float* __restrict__ src,
                        __hip_bfloat16* __restrict__ dst, int n) {
  int i = blockIdx.x * blockDim.x + threadIdx.x;
  if (i >= n) return;
  dst[i] = __float2bfloat16(src[i]);
}

__global__ void k_zero(float* __restrict__ mem1, ushort* __restrict__ spk0, int n) {
  int i = blockIdx.x * blockDim.x + threadIdx.x;
  if (i >= n) return;
  mem1[i] = 0.0f;
  spk0[i] = 0;  // bf16 +0.0
}

// ---------------- persistent LSM loop ----------------
// block = (ks = blockIdx>>6, nchunk = blockIdx&63). Tile: M=64 (batch),
// N=64 (hidden units nbase..nbase+63), K-range [ks*640, ks*640+640).
// 4 waves: wave w owns n-sub [w*16, w*16+16), loops 4 M-frags.
// LDS tiles [64][BK=64] bf16 with byte-swizzle col ^= ((row&7)<<4).
__global__ __launch_bounds__(256, 2)
void k_lsm_persist(const __hip_bfloat16* __restrict__ xb,    // [T][B][IN_F]
                   __hip_bfloat16* __restrict__ spk,         // [T+1][B][HID]
                   const __hip_bfloat16* __restrict__ w1hi,  // [HID][TOTAL]
                   const __hip_bfloat16* __restrict__ w1lo,
                   float* __restrict__ mem1,                 // [B][HID]
                   const float* __restrict__ beta,           // [HID]
                   const float* __restrict__ thr,            // [HID]
                   float* __restrict__ part) {               // [KSPLIT][B][HID]
  cg::grid_group grid = cg::this_grid();

  __shared__ __align__(16) short lA[2][64 * BK];
  __shared__ __align__(16) short lBh[2][64 * BK];
  __shared__ __align__(16) short lBl[2][64 * BK];

  const int tid    = threadIdx.x;
  const int lane   = tid & 63;
  const int w      = tid >> 6;
  const int nchunk = blockIdx.x & 63;
  const int ks     = blockIdx.x >> 6;
  const int nbase  = nchunk * 64;
  const int kbase  = ks * KPB;

  // staging geometry: thread stages 16 elems (two 16B chunks) of each tile row
  const int rS   = tid >> 2;          // tile row 0..63
  const int cEl  = (tid & 3) * 16;    // element col 0,16,32,48
  const int swzX = (rS & 7) << 4;
  const int stByte0 = rS * 128 + ((cEl * 2) ^ swzX);
  const int stByte1 = rS * 128 + ((cEl * 2 + 16) ^ swzX);

  // fragment geometry
  const int fr     = lane & 15;
  const int fkB    = (lane >> 4) * 16;   // byte offset of 8-elem group
  const int frSwz  = (fr & 7) << 4;

  f32x4 acc[4];
  bf16x8 rgA[6], rgB[6];

  auto DSWRITE = [&](int ibuf, bf16x8* R) {
    *(bf16x8*)((char*)lA[ibuf] + stByte0)  = R[0];
    *(bf16x8*)((char*)lA[ibuf] + stByte1)  = R[1];
    *(bf16x8*)((char*)lBh[ibuf] + stByte0) = R[2];
    *(bf16x8*)((char*)lBh[ibuf] + stByte1) = R[3];
    *(bf16x8*)((char*)lBl[ibuf] + stByte0) = R[4];
    *(bf16x8*)((char*)lBl[ibuf] + stByte1) = R[5];
  };

  auto COMPUTE = [&](int ibuf) {
    const char* pA  = (const char*)lA[ibuf];
    const char* pBh = (const char*)lBh[ibuf];
    const char* pBl = (const char*)lBl[ibuf];
#pragma unroll
    for (int s = 0; s < 2; ++s) {
      const int co = ((s * 64 + fkB) ^ frSwz);
      bf16x8 fbh = *(const bf16x8*)(pBh + (w * 16 + fr) * 128 + co);
      bf16x8 fbl = *(const bf16x8*)(pBl + (w * 16 + fr) * 128 + co);
#pragma unroll
      for (int m = 0; m < 4; ++m) {
        bf16x8 fa = *(const bf16x8*)(pA + (m * 16 + fr) * 128 + co);
        acc[m] = __builtin_amdgcn_mfma_f32_16x16x32_bf16(fa, fbh, acc[m], 0, 0, 0);
        acc[m] = __builtin_amdgcn_mfma_f32_16x16x32_bf16(fa, fbl, acc[m], 0, 0, 0);
      }
    }
  };

  for (int t = 0; t < T_STEPS; ++t) {
    const __hip_bfloat16* xt   = xb  + (size_t)t * BATCH * IN_F;
    const __hip_bfloat16* spkt = spk + (size_t)t * BATCH * HID;

    auto GLOAD = [&](int it, bf16x8* R) {
      const int k0g = kbase + it * BK;   // tile is purely x or purely spikes
      const __hip_bfloat16* asrc =
          (k0g < IN_F) ? xt   + (size_t)rS * IN_F + (k0g + cEl)
                       : spkt + (size_t)rS * HID + (k0g - IN_F + cEl);
      R[0] = *(const bf16x8*)(asrc);
      R[1] = *(const bf16x8*)(asrc + 8);
      const __hip_bfloat16* hsrc = w1hi + (size_t)(nbase + rS) * TOTAL + (k0g + cEl);
      R[2] = *(const bf16x8*)(hsrc);
      R[3] = *(const bf16x8*)(hsrc + 8);
      const __hip_bfloat16* lsrc = w1lo + (size_t)(nbase + rS) * TOTAL + (k0g + cEl);
      R[4] = *(const bf16x8*)(lsrc);
      R[5] = *(const bf16x8*)(lsrc + 8);
    };

#pragma unroll
    for (int m = 0; m < 4; ++m) acc[m] = (f32x4){0.f, 0.f, 0.f, 0.f};

    // prologue: tile 0 -> buf0
    GLOAD(0, rgA);
    DSWRITE(0, rgA);
    __syncthreads();

    for (int itp = 0; itp < NIT / 2; ++itp) {
      const int it = itp * 2;
      GLOAD(it + 1, rgB);        // issue next-tile loads early
      COMPUTE(0);                // compute on buf0
      DSWRITE(1, rgB);           // implicit vmcnt wait here
      __syncthreads();
      if (it + 2 < NIT) {
        GLOAD(it + 2, rgA);
        COMPUTE(1);
        DSWRITE(0, rgA);
        __syncthreads();
      } else {
        COMPUTE(1);
      }
    }

    // write K-split partials. C/D layout: col(lane&15)=n, row=(lane>>4)*4+q=batch
    {
      const int nglob = nbase + w * 16 + fr;
      const int brow  = (lane >> 4) * 4;
      float* pp = part + (size_t)ks * (BATCH * HID);
#pragma unroll
      for (int m = 0; m < 4; ++m) {
#pragma unroll
        for (int q = 0; q < 4; ++q) {
          pp[(size_t)(m * 16 + brow + q) * HID + nglob] = acc[m][q];
        }
      }
    }

    grid.sync();

    // reduce partials (fixed ks order -> deterministic) + LIF + spike write
    {
      const int o0 = blockIdx.x * 512 + tid;
#pragma unroll
      for (int u = 0; u < 2; ++u) {
        const int o = o0 + u * 256;          // flat b*HID + n
        const int n = o & (HID - 1);
        float c = 0.f;
#pragma unroll
        for (int k2 = 0; k2 < KSPLIT; ++k2)
          c += part[(size_t)k2 * (BATCH * HID) + o];
        float mv = mem1[o] - beta[n] + c;
        mv = fmaxf(mv, 0.f);                 // state_quant = relu
        const float s = (mv > thr[n]) ? 1.f : 0.f;
        mv -= s * thr[n];                    // reset by subtract
        mem1[o] = mv;
        spk[(size_t)(t + 1) * BATCH * HID + o] = __float2bfloat16(s);
      }
    }

    grid.sync();
  }
}

// ---------------- readout GEMM: cur2 = spk_rec @ w2^T + b2 ----------------
__global__ __launch_bounds__(256)
void k_ro_gemm(const __hip_bfloat16* __restrict__ A,      // [8192][HID]
               const __hip_bfloat16* __restrict__ w2hi,   // [OUT_F][HID]
               const __hip_bfloat16* __restrict__ w2lo,
               const float* __restrict__ b2,
               float* __restrict__ cur2) {                // [8192][OUT_F]
  __shared__ __align__(16) short lA[64 * 32];
  __shared__ __align__(16) short lBh[64 * 32];
  __shared__ __align__(16) short lBl[64 * 32];

  const int tid  = threadIdx.x;
  const int lane = tid & 63;
  const int w    = tid >> 6;
  const int mt = blockIdx.x >> 3;
  const int nt = blockIdx.x & 7;
  const int mbase = mt * 64;
  const int nbase = nt * 64;

  f32x4 acc0 = {0.f, 0.f, 0.f, 0.f};
  f32x4 acc1 = {0.f, 0.f, 0.f, 0.f};
  f32x4 acc2 = {0.f, 0.f, 0.f, 0.f};
  f32x4 acc3 = {0.f, 0.f, 0.f, 0.f};

  const int r  = tid >> 2;
  const int kc = (tid & 3) * 8;
  const int fr = lane & 15;
  const int fk = (lane >> 4) * 8;

  for (int kt = 0; kt < HID / 32; ++kt) {
    const int k0 = kt * 32;
    __syncthreads();
    bf16x8 av = *reinterpret_cast<const bf16x8*>(A    + (size_t)(mbase + r) * HID + k0 + kc);
    bf16x8 bh = *reinterpret_cast<const bf16x8*>(w2hi + (size_t)(nbase + r) * HID + k0 + kc);
    bf16x8 bl = *reinterpret_cast<const bf16x8*>(w2lo + (size_t)(nbase + r) * HID + k0 + kc);
    *reinterpret_cast<bf16x8*>(&lA[r * 32 + kc])  = av;
    *reinterpret_cast<bf16x8*>(&lBh[r * 32 + kc]) = bh;
    *reinterpret_cast<bf16x8*>(&lBl[r * 32 + kc]) = bl;
    __syncthreads();

    bf16x8 fbh = *reinterpret_cast<const bf16x8*>(&lBh[(w * 16 + fr) * 32 + fk]);
    bf16x8 fbl = *reinterpret_cast<const bf16x8*>(&lBl[(w * 16 + fr) * 32 + fk]);
    bf16x8 fa0 = *reinterpret_cast<const bf16x8*>(&lA[(0 * 16 + fr) * 32 + fk]);
    bf16x8 fa1 = *reinterpret_cast<const bf16x8*>(&lA[(1 * 16 + fr) * 32 + fk]);
    bf16x8 fa2 = *reinterpret_cast<const bf16x8*>(&lA[(2 * 16 + fr) * 32 + fk]);
    bf16x8 fa3 = *reinterpret_cast<const bf16x8*>(&lA[(3 * 16 + fr) * 32 + fk]);

    acc0 = __builtin_amdgcn_mfma_f32_16x16x32_bf16(fa0, fbh, acc0, 0, 0, 0);
    acc0 = __builtin_amdgcn_mfma_f32_16x16x32_bf16(fa0, fbl, acc0, 0, 0, 0);
    acc1 = __builtin_amdgcn_mfma_f32_16x16x32_bf16(fa1, fbh, acc1, 0, 0, 0);
    acc1 = __builtin_amdgcn_mfma_f32_16x16x32_bf16(fa1, fbl, acc1, 0, 0, 0);
    acc2 = __builtin_amdgcn_mfma_f32_16x16x32_bf16(fa2, fbh, acc2, 0, 0, 0);
    acc2 = __builtin_amdgcn_mfma_f32_16x16x32_bf16(fa2, fbl, acc2, 0, 0, 0);
    acc3 = __builtin_amdgcn_mfma_f32_16x16x32_bf16(fa3, fbh, acc3, 0, 0, 0);
    acc3 = __builtin_amdgcn_mfma_f32_16x16x32_bf16(fa3, fbl, acc3, 0, 0, 0);
  }

  const int col = nbase + w * 16 + (lane & 15);
  const float bias = b2[col];
  const int brow = (lane >> 4) * 4;
#define RO_EPI(ACC, M)                                        \
  {                                                           \
    _Pragma("unroll")                                         \
    for (int q = 0; q < 4; ++q) {                             \
      const int row = mbase + (M) * 16 + brow + q;            \
      cur2[(size_t)row * OUT_F + col] = (ACC)[q] + bias;      \
    }                                                         \
  }
  RO_EPI(acc0, 0)
  RO_EPI(acc1, 1)
  RO_EPI(acc2, 2)
  RO_EPI(acc3, 3)
#undef RO_EPI
}

// ---------------- readout LIF scan ----------------
__global__ void k_ro_scan(const float* __restrict__ cur2,
                          const float* __restrict__ beta,
                          const float* __restrict__ thr,
                          float* __restrict__ out) {
  const int i = blockIdx.x * blockDim.x + threadIdx.x;
  const int b = i >> 9;
  const int o = i & (OUT_F - 1);
  const float bt = beta[o];
  const float th = thr[o];
  float m = 0.0f;
  for (int t = 0; t < T_STEPS; ++t) {
    const size_t idx = (size_t)(t * BATCH + b) * OUT_F + o;
    m = m - bt + cur2[idx];
    const float s = (m > th) ? 1.0f : 0.0f;
    m -= s * th;
    out[idx] = s;
  }
}

// ---------------- launch ----------------
extern "C" void kernel_launch(void* const* d_in, const int* in_sizes, int n_in,
                              void* d_out, int out_size, void* d_ws, size_t ws_size,
                              hipStream_t stream) {
  const float* x        = (const float*)d_in[0];
  const float* w1       = (const float*)d_in[1];
  const float* w2       = (const float*)d_in[2];
  const float* b2       = (const float*)d_in[3];
  const float* beta_lsm = (const float*)d_in[4];
  const float* thr_lsm  = (const float*)d_in[5];
  const float* beta_ro  = (const float*)d_in[6];
  const float* thr_ro   = (const float*)d_in[7];
  float* out = (float*)d_out;

  char* ws = (char*)d_ws;
  size_t off = 0;
  auto alloc = [&](size_t bytes) -> char* {
    char* p = ws + off;
    off += (bytes + 255) & ~(size_t)255;
    return p;
  };
  __hip_bfloat16* w1hi = (__hip_bfloat16*)alloc((size_t)HID * TOTAL * 2);
  __hip_bfloat16* w1lo = (__hip_bfloat16*)alloc((size_t)HID * TOTAL * 2);
  __hip_bfloat16* xb   = (__hip_bfloat16*)alloc((size_t)T_STEPS * BATCH * IN_F * 2);
  __hip_bfloat16* spk  = (__hip_bfloat16*)alloc((size_t)(T_STEPS + 1) * BATCH * HID * 2);
  __hip_bfloat16* w2hi = (__hip_bfloat16*)alloc((size_t)OUT_F * HID * 2);
  __hip_bfloat16* w2lo = (__hip_bfloat16*)alloc((size_t)OUT_F * HID * 2);
  float* mem1 = (float*)alloc((size_t)BATCH * HID * 4);
  float* cur2 = (float*)alloc((size_t)T_STEPS * BATCH * OUT_F * 4);
  float* part = (float*)alloc((size_t)KSPLIT * BATCH * HID * 4);

  // prep
  {
    int n4 = HID * TOTAL / 4;
    k_cvt_split<<<(n4 + 255) / 256, 256, 0, stream>>>(w1, w1hi, w1lo, n4);
  }
  {
    int n4 = OUT_F * HID / 4;
    k_cvt_split<<<(n4 + 255) / 256, 256, 0, stream>>>(w2, w2hi, w2lo, n4);
  }
  {
    int n = T_STEPS * BATCH * IN_F;
    k_cvt_x<<<(n + 255) / 256, 256, 0, stream>>>(x, xb, n);
  }
  {
    int n = BATCH * HID;
    k_zero<<<(n + 255) / 256, 256, 0, stream>>>(mem1, (ushort*)spk, n);
  }

  // persistent cooperative reservoir loop (512 blocks = 2/CU co-resident)
  {
    const __hip_bfloat16* xb_c = xb;
    void* kargs[] = {(void*)&xb_c,     (void*)&spk,      (void*)&w1hi,
                     (void*)&w1lo,     (void*)&mem1,     (void*)&beta_lsm,
                     (void*)&thr_lsm,  (void*)&part};
    hipLaunchCooperativeKernel((const void*)k_lsm_persist, dim3(512), dim3(256),
                               kargs, 0, stream);
  }

  // readout
  k_ro_gemm<<<(T_STEPS * BATCH / 64) * (OUT_F / 64), 256, 0, stream>>>(
      spk + (size_t)BATCH * HID, w2hi, w2lo, b2, cur2);
  k_ro_scan<<<(BATCH * OUT_F) / 256, 256, 0, stream>>>(cur2, beta_ro, thr_ro, out);
}

// Round 3
// 2399.292 us; speedup vs baseline: 7.3499x; 7.3499x over previous
//
#include <hip/hip_runtime.h>
#include <hip/hip_bf16.h>

// LSMPool round 3: one kernel launch per reservoir step (kernel boundary =
// grid sync; coop grid.sync() measured ~65us/sync in round 2 -> dropped).
// Step kernel: 256 blocks x 256 thr (4 waves). Block owns N=16 hidden units,
// M=64 batch, FULL K=5120 (so LIF fuses in-kernel, no partials):
//   - K split 4-way across waves (wave w: k in [w*1280, w*1280+1280)).
//   - Barrier-free K-loop: per-wave private LDS windows (BK=64), triple-
//     buffered, staged with global_load_lds width=16 using PRE-SWIZZLED
//     global source (chunk ^= row&7) so ds_read_b128 frags are conflict-free.
//   - Counted s_waitcnt vmcnt(24/12/0): loads stay in flight across windows.
//   - Epilogue: cross-wave reduce in LDS (fixed order, deterministic) + LIF.
// Readout GEMM + scan unchanged (absmax was 0.0).

namespace {
constexpr int T_STEPS = 128;
constexpr int BATCH   = 64;
constexpr int IN_F    = 1024;
constexpr int HID     = 4096;
constexpr int OUT_F   = 512;
constexpr int TOTAL   = IN_F + HID;   // 5120
constexpr int NWAVE   = 4;
constexpr int KW      = TOTAL / NWAVE; // 1280 per wave
constexpr int BK      = 64;
constexpr int NIT     = KW / BK;       // 20 windows per wave
// per-wave LDS region: 3 bufs x (A 64x64 bf16 = 8KB, Bh 2KB, Bl 2KB) = 36864 B
constexpr int BUFB    = 12288;
constexpr int WREGB   = 3 * BUFB;      // 36864
constexpr int SMEMB   = NWAVE * WREGB; // 147456 (<160KB LDS/CU)
}

using bf16x8 = __attribute__((ext_vector_type(8))) short;
using f32x4  = __attribute__((ext_vector_type(4))) float;

__device__ __forceinline__ void gload_lds16(const void* g, void* l) {
  __builtin_amdgcn_global_load_lds(
      (const __attribute__((address_space(1))) unsigned int*)(g),
      (__attribute__((address_space(3))) unsigned int*)(l), 16, 0, 0);
}

// ---------------- prep kernels ----------------

__global__ void k_cvt_split(const float* __restrict__ src,
                            __hip_bfloat16* __restrict__ hi,
                            __hip_bfloat16* __restrict__ lo, int n4) {
  int i = blockIdx.x * blockDim.x + threadIdx.x;
  if (i >= n4) return;
  float4 v = reinterpret_cast<const float4*>(src)[i];
#define CVT1(J, F)                                                        \
  {                                                                       \
    __hip_bfloat16 hb = __float2bfloat16(F);                              \
    hi[4 * (size_t)i + J] = hb;                                           \
    lo[4 * (size_t)i + J] = __float2bfloat16((F) - __bfloat162float(hb)); \
  }
  CVT1(0, v.x) CVT1(1, v.y) CVT1(2, v.z) CVT1(3, v.w)
#undef CVT1
}

__global__ void k_cvt_x(const float* __restrict__ src,
                        __hip_bfloat16* __restrict__ dst, int n) {
  int i = blockIdx.x * blockDim.x + threadIdx.x;
  if (i >= n) return;
  dst[i] = __float2bfloat16(src[i]);
}

__global__ void k_zero(float* __restrict__ mem1, ushort* __restrict__ spk0, int n) {
  int i = blockIdx.x * blockDim.x + threadIdx.x;
  if (i >= n) return;
  mem1[i] = 0.0f;
  spk0[i] = 0;  // bf16 +0.0
}

// ---------------- per-step fused GEMM + LIF ----------------
__global__ __launch_bounds__(256, 1)
void k_step(int t,
            const __hip_bfloat16* __restrict__ xb,    // [T][B][IN_F]
            __hip_bfloat16* __restrict__ spk,         // [T+1][B][HID]
            const __hip_bfloat16* __restrict__ w1hi,  // [HID][TOTAL]
            const __hip_bfloat16* __restrict__ w1lo,
            float* __restrict__ mem1,                 // [B][HID]
            const float* __restrict__ beta,           // [HID]
            const float* __restrict__ thr) {          // [HID]
  __shared__ __align__(16) char smem[SMEMB];

  const int tid   = threadIdx.x;
  const int l     = tid & 63;
  const int wv    = tid >> 6;
  const int nbase = blockIdx.x * 16;
  const int kwave = wv * KW;

  const __hip_bfloat16* xbt  = xb  + (size_t)t * BATCH * IN_F;
  const __hip_bfloat16* spkt = spk + (size_t)t * BATCH * HID;

  // --- staging per-lane geometry (one gload_lds16 = 8 rows x 8 chunks) ---
  // lane l -> row_in_group = l>>3, chunk slot = l&7; source chunk pre-swizzled
  // by XOR row&7 (= l>>3 since groups are 8-row aligned).
  const int jrow = l >> 3;
  const int swz  = ((l & 7) ^ jrow) * 8;   // element offset of source chunk
  const int aX = jrow * IN_F + swz;        // A row-offset, x region
  const int aS = jrow * HID + swz;         // A row-offset, spike region
  const int bO = jrow * TOTAL + swz;       // B (w1) row-offset

  // --- fragment per-lane geometry (ds_read_b128, conflict-free via swizzle) --
  const int rA  = (l & 15) * 128;                       // row byte offset
  const int cs0 = (((l >> 4) ^ (l & 7)) * 16);          // k32 s=0 chunk byte
  const int cs1 = ((((l >> 4) + 4) ^ (l & 7)) * 16);    // k32 s=1 chunk byte

  char* const wbase = smem + (size_t)wv * WREGB;

  f32x4 acc[4];
#pragma unroll
  for (int mf = 0; mf < 4; ++mf) acc[mf] = (f32x4){0.f, 0.f, 0.f, 0.f};

  auto ISSUE = [&](int it, char* ldsw) {
    const int k0 = kwave + it * BK;
    if (k0 < IN_F) {
      const __hip_bfloat16* ab = xbt + k0 + aX;
#pragma unroll
      for (int j = 0; j < 8; ++j)
        gload_lds16(ab + j * 8 * IN_F, ldsw + j * 1024);
    } else {
      const __hip_bfloat16* ab = spkt + (k0 - IN_F) + aS;
#pragma unroll
      for (int j = 0; j < 8; ++j)
        gload_lds16(ab + j * 8 * HID, ldsw + j * 1024);
    }
    const __hip_bfloat16* hb = w1hi + (size_t)nbase * TOTAL + k0 + bO;
    const __hip_bfloat16* lb = w1lo + (size_t)nbase * TOTAL + k0 + bO;
    gload_lds16(hb,             ldsw + 8192);
    gload_lds16(hb + 8 * TOTAL, ldsw + 9216);
    gload_lds16(lb,             ldsw + 10240);
    gload_lds16(lb + 8 * TOTAL, ldsw + 11264);
  };

  auto COMP = [&](char* ldsw) {
#pragma unroll
    for (int s = 0; s < 2; ++s) {
      const int cs = s ? cs1 : cs0;
      bf16x8 bh = *(const bf16x8*)(ldsw + 8192  + rA + cs);
      bf16x8 bl = *(const bf16x8*)(ldsw + 10240 + rA + cs);
#pragma unroll
      for (int mf = 0; mf < 4; ++mf) {
        bf16x8 a = *(const bf16x8*)(ldsw + mf * 2048 + rA + cs);
        acc[mf] = __builtin_amdgcn_mfma_f32_16x16x32_bf16(a, bh, acc[mf], 0, 0, 0);
        acc[mf] = __builtin_amdgcn_mfma_f32_16x16x32_bf16(a, bl, acc[mf], 0, 0, 0);
      }
    }
  };

  // --- pipelined K-loop (depth 3, wave-private, no block barriers) ---
  char* p0 = wbase;
  char* p1 = wbase + BUFB;
  char* p2 = wbase + 2 * BUFB;
  ISSUE(0, p0);
  ISSUE(1, p1);
  ISSUE(2, p2);
  for (int i = 0; i < NIT - 3; ++i) {
    asm volatile("s_waitcnt vmcnt(24)" ::: "memory");  // window i landed
    COMP(p0);
    ISSUE(i + 3, p0);                                  // reuse just-consumed buf
    char* tmp = p0; p0 = p1; p1 = p2; p2 = tmp;
  }
  asm volatile("s_waitcnt vmcnt(24)" ::: "memory");
  COMP(p0);
  asm volatile("s_waitcnt vmcnt(12)" ::: "memory");
  COMP(p1);
  asm volatile("s_waitcnt vmcnt(0)" ::: "memory");
  COMP(p2);

  // --- cross-wave reduce (fixed order = deterministic) + LIF ---
  __syncthreads();   // all waves done with LDS staging/reads
  float* red = (float*)smem;     // 4 waves x 1024 f32 = 16KB
#pragma unroll
  for (int mf = 0; mf < 4; ++mf) {
#pragma unroll
    for (int q = 0; q < 4; ++q) {
      const int m = mf * 16 + (l >> 4) * 4 + q;      // batch row
      red[wv * 1024 + m * 16 + (l & 15)] = acc[mf][q];
    }
  }
  __syncthreads();

  __hip_bfloat16* spk_out = spk + (size_t)(t + 1) * BATCH * HID;
#pragma unroll
  for (int u = 0; u < 4; ++u) {
    const int o = tid + u * 256;                 // m*16 + n, 0..1023
    const float c = (red[o] + red[o + 1024]) + (red[o + 2048] + red[o + 3072]);
    const int m  = o >> 4;
    const int ng = nbase + (o & 15);
    const size_t gi = (size_t)m * HID + ng;
    float mv = mem1[gi] - beta[ng] + c;
    mv = fmaxf(mv, 0.f);                         // state_quant = relu
    const float s = (mv > thr[ng]) ? 1.f : 0.f;
    mv -= s * thr[ng];                           // reset by subtract
    mem1[gi] = mv;
    spk_out[gi] = __float2bfloat16(s);
  }
}

// ---------------- readout GEMM: cur2 = spk_rec @ w2^T + b2 ----------------
__global__ __launch_bounds__(256)
void k_ro_gemm(const __hip_bfloat16* __restrict__ A,      // [8192][HID]
               const __hip_bfloat16* __restrict__ w2hi,   // [OUT_F][HID]
               const __hip_bfloat16* __restrict__ w2lo,
               const float* __restrict__ b2,
               float* __restrict__ cur2) {                // [8192][OUT_F]
  __shared__ __align__(16) short lA[64 * 32];
  __shared__ __align__(16) short lBh[64 * 32];
  __shared__ __align__(16) short lBl[64 * 32];

  const int tid  = threadIdx.x;
  const int lane = tid & 63;
  const int w    = tid >> 6;
  const int mt = blockIdx.x >> 3;
  const int nt = blockIdx.x & 7;
  const int mbase = mt * 64;
  const int nbase = nt * 64;

  f32x4 acc0 = {0.f, 0.f, 0.f, 0.f};
  f32x4 acc1 = {0.f, 0.f, 0.f, 0.f};
  f32x4 acc2 = {0.f, 0.f, 0.f, 0.f};
  f32x4 acc3 = {0.f, 0.f, 0.f, 0.f};

  const int r  = tid >> 2;
  const int kc = (tid & 3) * 8;
  const int fr = lane & 15;
  const int fk = (lane >> 4) * 8;

  for (int kt = 0; kt < HID / 32; ++kt) {
    const int k0 = kt * 32;
    __syncthreads();
    bf16x8 av = *reinterpret_cast<const bf16x8*>(A    + (size_t)(mbase + r) * HID + k0 + kc);
    bf16x8 bh = *reinterpret_cast<const bf16x8*>(w2hi + (size_t)(nbase + r) * HID + k0 + kc);
    bf16x8 bl = *reinterpret_cast<const bf16x8*>(w2lo + (size_t)(nbase + r) * HID + k0 + kc);
    *reinterpret_cast<bf16x8*>(&lA[r * 32 + kc])  = av;
    *reinterpret_cast<bf16x8*>(&lBh[r * 32 + kc]) = bh;
    *reinterpret_cast<bf16x8*>(&lBl[r * 32 + kc]) = bl;
    __syncthreads();

    bf16x8 fbh = *reinterpret_cast<const bf16x8*>(&lBh[(w * 16 + fr) * 32 + fk]);
    bf16x8 fbl = *reinterpret_cast<const bf16x8*>(&lBl[(w * 16 + fr) * 32 + fk]);
    bf16x8 fa0 = *reinterpret_cast<const bf16x8*>(&lA[(0 * 16 + fr) * 32 + fk]);
    bf16x8 fa1 = *reinterpret_cast<const bf16x8*>(&lA[(1 * 16 + fr) * 32 + fk]);
    bf16x8 fa2 = *reinterpret_cast<const bf16x8*>(&lA[(2 * 16 + fr) * 32 + fk]);
    bf16x8 fa3 = *reinterpret_cast<const bf16x8*>(&lA[(3 * 16 + fr) * 32 + fk]);

    acc0 = __builtin_amdgcn_mfma_f32_16x16x32_bf16(fa0, fbh, acc0, 0, 0, 0);
    acc0 = __builtin_amdgcn_mfma_f32_16x16x32_bf16(fa0, fbl, acc0, 0, 0, 0);
    acc1 = __builtin_amdgcn_mfma_f32_16x16x32_bf16(fa1, fbh, acc1, 0, 0, 0);
    acc1 = __builtin_amdgcn_mfma_f32_16x16x32_bf16(fa1, fbl, acc1, 0, 0, 0);
    acc2 = __builtin_amdgcn_mfma_f32_16x16x32_bf16(fa2, fbh, acc2, 0, 0, 0);
    acc2 = __builtin_amdgcn_mfma_f32_16x16x32_bf16(fa2, fbl, acc2, 0, 0, 0);
    acc3 = __builtin_amdgcn_mfma_f32_16x16x32_bf16(fa3, fbh, acc3, 0, 0, 0);
    acc3 = __builtin_amdgcn_mfma_f32_16x16x32_bf16(fa3, fbl, acc3, 0, 0, 0);
  }

  const int col = nbase + w * 16 + (lane & 15);
  const float bias = b2[col];
  const int brow = (lane >> 4) * 4;
#define RO_EPI(ACC, M)                                        \
  {                                                           \
    _Pragma("unroll")                                         \
    for (int q = 0; q < 4; ++q) {                             \
      const int row = mbase + (M) * 16 + brow + q;            \
      cur2[(size_t)row * OUT_F + col] = (ACC)[q] + bias;      \
    }                                                         \
  }
  RO_EPI(acc0, 0)
  RO_EPI(acc1, 1)
  RO_EPI(acc2, 2)
  RO_EPI(acc3, 3)
#undef RO_EPI
}

// ---------------- readout LIF scan ----------------
__global__ void k_ro_scan(const float* __restrict__ cur2,
                          const float* __restrict__ beta,
                          const float* __restrict__ thr,
                          float* __restrict__ out) {
  const int i = blockIdx.x * blockDim.x + threadIdx.x;
  const int b = i >> 9;
  const int o = i & (OUT_F - 1);
  const float bt = beta[o];
  const float th = thr[o];
  float m = 0.0f;
  for (int t = 0; t < T_STEPS; ++t) {
    const size_t idx = (size_t)(t * BATCH + b) * OUT_F + o;
    m = m - bt + cur2[idx];
    const float s = (m > th) ? 1.0f : 0.0f;
    m -= s * th;
    out[idx] = s;
  }
}

// ---------------- launch ----------------
extern "C" void kernel_launch(void* const* d_in, const int* in_sizes, int n_in,
                              void* d_out, int out_size, void* d_ws, size_t ws_size,
                              hipStream_t stream) {
  const float* x        = (const float*)d_in[0];
  const float* w1       = (const float*)d_in[1];
  const float* w2       = (const float*)d_in[2];
  const float* b2       = (const float*)d_in[3];
  const float* beta_lsm = (const float*)d_in[4];
  const float* thr_lsm  = (const float*)d_in[5];
  const float* beta_ro  = (const float*)d_in[6];
  const float* thr_ro   = (const float*)d_in[7];
  float* out = (float*)d_out;

  char* ws = (char*)d_ws;
  size_t off = 0;
  auto alloc = [&](size_t bytes) -> char* {
    char* p = ws + off;
    off += (bytes + 255) & ~(size_t)255;
    return p;
  };
  __hip_bfloat16* w1hi = (__hip_bfloat16*)alloc((size_t)HID * TOTAL * 2);
  __hip_bfloat16* w1lo = (__hip_bfloat16*)alloc((size_t)HID * TOTAL * 2);
  __hip_bfloat16* xb   = (__hip_bfloat16*)alloc((size_t)T_STEPS * BATCH * IN_F * 2);
  __hip_bfloat16* spk  = (__hip_bfloat16*)alloc((size_t)(T_STEPS + 1) * BATCH * HID * 2);
  __hip_bfloat16* w2hi = (__hip_bfloat16*)alloc((size_t)OUT_F * HID * 2);
  __hip_bfloat16* w2lo = (__hip_bfloat16*)alloc((size_t)OUT_F * HID * 2);
  float* mem1 = (float*)alloc((size_t)BATCH * HID * 4);
  float* cur2 = (float*)alloc((size_t)T_STEPS * BATCH * OUT_F * 4);

  // prep
  {
    int n4 = HID * TOTAL / 4;
    k_cvt_split<<<(n4 + 255) / 256, 256, 0, stream>>>(w1, w1hi, w1lo, n4);
  }
  {
    int n4 = OUT_F * HID / 4;
    k_cvt_split<<<(n4 + 255) / 256, 256, 0, stream>>>(w2, w2hi, w2lo, n4);
  }
  {
    int n = T_STEPS * BATCH * IN_F;
    k_cvt_x<<<(n + 255) / 256, 256, 0, stream>>>(x, xb, n);
  }
  {
    int n = BATCH * HID;
    k_zero<<<(n + 255) / 256, 256, 0, stream>>>(mem1, (ushort*)spk, n);
  }

  // sequential reservoir steps: one kernel per step (stream order = sync)
  for (int t = 0; t < T_STEPS; ++t) {
    k_step<<<HID / 16, 256, 0, stream>>>(t, xb, spk, w1hi, w1lo, mem1,
                                         beta_lsm, thr_lsm);
  }

  // readout
  k_ro_gemm<<<(T_STEPS * BATCH / 64) * (OUT_F / 64), 256, 0, stream>>>(
      spk + (size_t)BATCH * HID, w2hi, w2lo, b2, cur2);
  k_ro_scan<<<(BATCH * OUT_F) / 256, 256, 0, stream>>>(cur2, beta_ro, thr_ro, out);
}